// Round 3
// baseline (367.132 us; speedup 1.0000x reference)
//
#include <hip/hip_runtime.h>
#include <math.h>

#define BB 512       // batch rows (M) == BM: one block spans all rows
#define DD 512       // depth (K)
#define CC 100000    // classes (N)
#define MARGIN2 0.5f
#define PI_F 3.14159265358979323846f

#define BN 80        // 100000 = 1250 * 80, no guards
#define BK 64
#define KSTEPS (DD / BK)   // 8

typedef __bf16 bf16x8 __attribute__((ext_vector_type(8)));
typedef float f32x4 __attribute__((ext_vector_type(4)));

static __device__ __forceinline__ unsigned short f2bf(float f) {
    union { float f; unsigned u; } v; v.f = f;
    unsigned r = v.u + 0x7FFFu + ((v.u >> 16) & 1u);   // round-to-nearest-even
    return (unsigned short)(r >> 16);
}

// swizzled LDS byte offset for row-major [row][64 x bf16] tiles (row stride 128B)
static __device__ __forceinline__ int swz(int row, int kbyte) {
    return row * 128 + (kbyte ^ ((row & 7) << 4));
}

// ---------------- K1: row-normalize x -> bf16 ----------------
__global__ __launch_bounds__(256) void k_norm_x(const float* __restrict__ x,
                                                unsigned short* __restrict__ xnb) {
    const int lane = threadIdx.x & 63;
    const int row  = blockIdx.x * 4 + (threadIdx.x >> 6);
    const float* xr = x + (size_t)row * DD;
    float4 v0 = *(const float4*)(xr + lane * 4);
    float4 v1 = *(const float4*)(xr + lane * 4 + 256);
    float s = v0.x*v0.x + v0.y*v0.y + v0.z*v0.z + v0.w*v0.w
            + v1.x*v1.x + v1.y*v1.y + v1.z*v1.z + v1.w*v1.w;
    #pragma unroll
    for (int m = 32; m; m >>= 1) s += __shfl_xor(s, m, 64);
    float rs = rsqrtf(fmaxf(s, 1e-12f));
    ushort4 o0, o1;
    o0.x = f2bf(v0.x * rs); o0.y = f2bf(v0.y * rs);
    o0.z = f2bf(v0.z * rs); o0.w = f2bf(v0.w * rs);
    o1.x = f2bf(v1.x * rs); o1.y = f2bf(v1.y * rs);
    o1.z = f2bf(v1.z * rs); o1.w = f2bf(v1.w * rs);
    *(ushort4*)(xnb + (size_t)row * DD + lane * 4)       = o0;
    *(ushort4*)(xnb + (size_t)row * DD + lane * 4 + 256) = o1;
}

// ---------------- K2: full-M bf16 MFMA GEMM, W read exactly once ----------------
// Block = 80-column W panel x all 512 rows. 8 waves, each wave: 64 rows x 80 cols
// = 4x5 fragments of 16x16. Column-norm fused; swapped-operand MFMA -> float4 stores.
__global__ __launch_bounds__(512, 2) void k_gemm(const unsigned short* __restrict__ xnb,
                                                 const float* __restrict__ W,
                                                 float* __restrict__ out) {
    __shared__ __align__(16) unsigned char Ash[BB * BK * 2];  // 64 KB, [row 0..511][64k] bf16 swz
    __shared__ __align__(16) unsigned char Bsh[BN * BK * 2];  // 10 KB, [n 0..79][64k] bf16 swz
    // after K loop: Bsh reused as float part[32][80] (10240 B), Ash head as float rn[80]

    const int tid = threadIdx.x;
    const int N0  = blockIdx.x * BN;

    // ---- A staging: 8 slots of 16B per thread (512x64 bf16 = 4096 slots) ----
    int a_goff[8], a_lds[8];
    #pragma unroll
    for (int i = 0; i < 8; ++i) {
        int s = i * 512 + tid;
        int row = s >> 3;          // 0..511
        int c8  = s & 7;           // 16B chunk within the 128B row
        a_goff[i] = row * DD + c8 * 8;
        a_lds[i]  = swz(row, c8 * 16);
    }

    // ---- B staging: 5 k-pair tasks per thread (80 n x 32 kp = 2560 tasks) ----
    int b_goff[5], b_lds[5];
    #pragma unroll
    for (int i = 0; i < 5; ++i) {
        int s = i * 512 + tid;     // slot s = kp*80 + n  (also the part[] index)
        int n  = s % BN;           // consecutive tid -> consecutive n (coalesced)
        int kp = s / BN;           // 0..31, pair of k's
        b_goff[i] = (kp * 2) * CC + N0 + n;
        b_lds[i]  = swz(n, kp * 4);
    }

    int4  areg[8];
    float breg[5][2];
    float bsq[5] = {0.f, 0.f, 0.f, 0.f, 0.f};   // column sumsq partials

    // prologue: prefetch tile t=0
    #pragma unroll
    for (int i = 0; i < 8; ++i)
        areg[i] = *(const int4*)(xnb + a_goff[i]);
    #pragma unroll
    for (int i = 0; i < 5; ++i) {
        const float* p = W + b_goff[i];
        breg[i][0] = p[0];
        breg[i][1] = p[CC];
    }

    const int lane = tid & 63;
    const int wid  = tid >> 6;     // 0..7 -> 64 rows each
    const int lr = lane & 15;
    const int lg = lane >> 4;

    f32x4 acc[4][5];
    #pragma unroll
    for (int mf = 0; mf < 4; ++mf)
        #pragma unroll
        for (int nf = 0; nf < 5; ++nf)
            acc[mf][nf] = (f32x4)0.f;

    for (int t = 0; t < KSTEPS; ++t) {
        __syncthreads();           // previous iteration done reading LDS
        #pragma unroll
        for (int i = 0; i < 8; ++i)
            *(int4*)(Ash + a_lds[i]) = areg[i];
        #pragma unroll
        for (int i = 0; i < 5; ++i) {
            bsq[i] += breg[i][0] * breg[i][0] + breg[i][1] * breg[i][1];
            unsigned w = (unsigned)f2bf(breg[i][0]) | ((unsigned)f2bf(breg[i][1]) << 16);
            *(unsigned*)(Bsh + b_lds[i]) = w;
        }
        __syncthreads();           // tile visible to all waves

        // prefetch next tile into registers (overlaps with MFMA below)
        if (t + 1 < KSTEPS) {
            #pragma unroll
            for (int i = 0; i < 8; ++i)
                areg[i] = *(const int4*)(xnb + a_goff[i] + (t + 1) * BK);
            #pragma unroll
            for (int i = 0; i < 5; ++i) {
                const float* p = W + b_goff[i] + (t + 1) * (BK * CC);
                breg[i][0] = p[0];
                breg[i][1] = p[CC];
            }
        }

        // compute: 2 k-substeps of 32, 4x5 fragments, operands swapped
        #pragma unroll
        for (int ks = 0; ks < 2; ++ks) {
            bf16x8 af[4], bfr[5];
            #pragma unroll
            for (int mf = 0; mf < 4; ++mf)
                af[mf] = *(const bf16x8*)(Ash + swz(wid * 64 + mf * 16 + lr, ks * 64 + lg * 16));
            #pragma unroll
            for (int nf = 0; nf < 5; ++nf)
                bfr[nf] = *(const bf16x8*)(Bsh + swz(nf * 16 + lr, ks * 64 + lg * 16));
            #pragma unroll
            for (int mf = 0; mf < 4; ++mf)
                #pragma unroll
                for (int nf = 0; nf < 5; ++nf)
                    acc[mf][nf] = __builtin_amdgcn_mfma_f32_16x16x32_bf16(
                        bfr[nf], af[mf], acc[mf][nf], 0, 0, 0);
        }
    }

    // ---- deterministic column-norm reduction in LDS (reuse Bsh/Ash) ----
    __syncthreads();                       // all waves done with LDS reads
    float* part = (float*)Bsh;             // [32][80] floats = 10240 B
    #pragma unroll
    for (int i = 0; i < 5; ++i)
        part[i * 512 + tid] = bsq[i];      // slot s = kp*80+n, unique owner
    __syncthreads();
    float* rn = (float*)Ash;               // [80] floats
    if (tid < BN) {
        float s = 0.f;
        #pragma unroll
        for (int k = 0; k < 32; ++k)
            s += part[k * BN + tid];       // fixed order -> deterministic
        rn[tid] = rsqrtf(fmaxf(s, 1e-12f));
    }
    __syncthreads();

    // ---- epilogue: scale by column rnorm, contiguous float4 stores ----
    #pragma unroll
    for (int nf = 0; nf < 5; ++nf) {
        const int nloc = nf * 16 + lg * 4;
        const f32x4 rn4 = *(const f32x4*)(rn + nloc);
        #pragma unroll
        for (int mf = 0; mf < 4; ++mf) {
            const size_t base = (size_t)(wid * 64 + mf * 16 + lr) * CC + N0 + nloc;
            f32x4 o;
            #pragma unroll
            for (int r = 0; r < 4; ++r)
                o[r] = acc[mf][nf][r] * rn4[r];
            *(f32x4*)(out + base) = o;
        }
    }
}

// ---------------- K3: margin fixup at label positions ----------------
__global__ __launch_bounds__(512) void k_fix(const int* __restrict__ lab,
                                             float* __restrict__ out) {
    const int b = threadIdx.x;
    const int c = lab[b];
    const size_t idx = (size_t)b * CC + c;
    float t = out[idx];
    t = fminf(fmaxf(t, -1.f), 1.f);
    float th = acosf(t) + MARGIN2;
    th = fminf(th, PI_F);              // min(t, t + (pi - stopgrad(t))) value-wise
    out[idx] = cosf(th);               // M3 == 0: no additive term
}

extern "C" void kernel_launch(void* const* d_in, const int* in_sizes, int n_in,
                              void* d_out, int out_size, void* d_ws, size_t ws_size,
                              hipStream_t stream) {
    const float* x   = (const float*)d_in[0];
    const float* W   = (const float*)d_in[1];
    const int*   lab = (const int*)d_in[2];
    float* out = (float*)d_out;

    unsigned short* xnb = (unsigned short*)d_ws;   // 512*512*2 = 512 KB scratch

    k_norm_x<<<dim3(BB / 4), dim3(256), 0, stream>>>(x, xnb);
    k_gemm<<<dim3(CC / BN), dim3(512), 0, stream>>>(xnb, W, out);
    k_fix<<<dim3(1), dim3(512), 0, stream>>>(lab, out);
}

// Round 4
// 211.716 us; speedup vs baseline: 1.7341x; 1.7341x over previous
//
#include <hip/hip_runtime.h>
#include <math.h>

#define BB 512       // batch rows (M)
#define DD 512       // depth (K)
#define CC 100000    // classes (N)
#define MARGIN2 0.5f
#define PI_F 3.14159265358979323846f

#define BM 128
#define BN 160
#define BK 64
#define KSTEPS (DD / BK)   // 8

typedef __bf16 bf16x8 __attribute__((ext_vector_type(8)));
typedef float f32x4 __attribute__((ext_vector_type(4)));

static __device__ __forceinline__ unsigned short f2bf(float f) {
    union { float f; unsigned u; } v; v.f = f;
    unsigned r = v.u + 0x7FFFu + ((v.u >> 16) & 1u);   // round-to-nearest-even
    return (unsigned short)(r >> 16);
}

// swizzled LDS byte offset for row-major [row][64 x bf16] tiles (row stride 128B)
static __device__ __forceinline__ int swz(int row, int kbyte) {
    return row * 128 + (kbyte ^ ((row & 7) << 4));
}

// ---------------- K1: row-normalize x -> bf16 ----------------
__global__ __launch_bounds__(256) void k_norm_x(const float* __restrict__ x,
                                                unsigned short* __restrict__ xnb) {
    const int lane = threadIdx.x & 63;
    const int row  = blockIdx.x * 4 + (threadIdx.x >> 6);
    const float* xr = x + (size_t)row * DD;
    float4 v0 = *(const float4*)(xr + lane * 4);
    float4 v1 = *(const float4*)(xr + lane * 4 + 256);
    float s = v0.x*v0.x + v0.y*v0.y + v0.z*v0.z + v0.w*v0.w
            + v1.x*v1.x + v1.y*v1.y + v1.z*v1.z + v1.w*v1.w;
    #pragma unroll
    for (int m = 32; m; m >>= 1) s += __shfl_xor(s, m, 64);
    float rs = rsqrtf(fmaxf(s, 1e-12f));
    ushort4 o0, o1;
    o0.x = f2bf(v0.x * rs); o0.y = f2bf(v0.y * rs);
    o0.z = f2bf(v0.z * rs); o0.w = f2bf(v0.w * rs);
    o1.x = f2bf(v1.x * rs); o1.y = f2bf(v1.y * rs);
    o1.z = f2bf(v1.z * rs); o1.w = f2bf(v1.w * rs);
    *(ushort4*)(xnb + (size_t)row * DD + lane * 4)       = o0;
    *(ushort4*)(xnb + (size_t)row * DD + lane * 4 + 256) = o1;
}

// ---------------- K2: bf16 MFMA GEMM, fused column-norm, line-aligned stores ----
// LDS aliasing:
//   GEMM phase : Ash = [0,16384)  A tile [128m][64k] bf16 swizzled
//                Bsh = [16384,36864) B tile [160n][64k] bf16 swizzled
//   NORM phase : part = floats at [16384, 16384+10240) (16 x 160)
//   STORE phase: staging = [0, 20992): 32 rows x 164 floats (padded stride)
//   rn[160] floats live at [36864, 37504) (dedicated, never aliased)
#define LDS_BYTES (36864 + 640)
#define ST_STRIDE 164   // floats per staging row (160 + 4 pad -> bank shift 4)

__global__ __launch_bounds__(512, 4) void k_gemm(const unsigned short* __restrict__ xnb,
                                                 const float* __restrict__ W,
                                                 float* __restrict__ out) {
    __shared__ __align__(16) unsigned char LDS[LDS_BYTES];
    unsigned char* Ash = LDS;
    unsigned char* Bsh = LDS + 16384;
    float* rn = (float*)(LDS + 36864);

    const int tid = threadIdx.x;
    const int bid = blockIdx.x;

    // bijective XCD swizzle: hw assigns block b -> XCD b%8; give each XCD a
    // contiguous v-range so the 4 mb-blocks of a panel share one XCD's L2.
    // 2500 = 8*312 + 4 -> XCDs 0..3 get 313 blocks, XCDs 4..7 get 312.
    const int xcd = bid & 7;
    const int jj  = bid >> 3;
    const int v   = (xcd < 4) ? (xcd * 313 + jj) : (1252 + (xcd - 4) * 312 + jj);
    const int mb  = v & 3;
    const int nb  = v >> 2;
    const int M0 = mb * BM;
    const int N0 = nb * BN;

    // ---- A staging: 2 slots of 16B per thread (128x64 bf16 tile = 1024 slots) ----
    int a_goff[2], a_lds[2];
    #pragma unroll
    for (int i = 0; i < 2; ++i) {
        int s = tid + i * 512;
        int row = s >> 3;
        int c8  = s & 7;
        a_goff[i] = (M0 + row) * DD + c8 * 8;
        a_lds[i]  = swz(row, c8 * 16);
    }

    // ---- B staging: 5 column-quad tasks per thread; s = kq*160 + n ----
    int b_goff[5], b_lds[5];
    #pragma unroll
    for (int i = 0; i < 5; ++i) {
        int s = tid + i * 512;
        int n  = s % BN;
        int kq = s / BN;
        b_goff[i] = (kq * 4) * CC + N0 + n;
        b_lds[i]  = n * 128 + ((kq * 8) ^ ((n & 7) << 4));
    }

    int4  areg[2];
    float breg[5][4];
    float bsq[5] = {0.f, 0.f, 0.f, 0.f, 0.f};   // column sumsq partials

    #pragma unroll
    for (int i = 0; i < 2; ++i)
        areg[i] = *(const int4*)(xnb + a_goff[i]);
    #pragma unroll
    for (int i = 0; i < 5; ++i) {
        const float* p = W + b_goff[i];
        breg[i][0] = p[0];
        breg[i][1] = p[CC];
        breg[i][2] = p[2 * CC];
        breg[i][3] = p[3 * CC];
    }

    const int lane = tid & 63;
    const int wid  = tid >> 6;
    const int wm = wid >> 1;       // 0..3 -> 32 rows each
    const int wn = wid & 1;        // 0..1 -> 80 cols each
    const int lr = lane & 15;
    const int lg = lane >> 4;

    f32x4 acc[2][5];
    #pragma unroll
    for (int mf = 0; mf < 2; ++mf)
        #pragma unroll
        for (int nf = 0; nf < 5; ++nf)
            acc[mf][nf] = (f32x4)0.f;

    for (int t = 0; t < KSTEPS; ++t) {
        __syncthreads();
        #pragma unroll
        for (int i = 0; i < 2; ++i)
            *(int4*)(Ash + a_lds[i]) = areg[i];
        #pragma unroll
        for (int i = 0; i < 5; ++i) {
            bsq[i] += breg[i][0] * breg[i][0] + breg[i][1] * breg[i][1]
                    + breg[i][2] * breg[i][2] + breg[i][3] * breg[i][3];
            uint2 w;
            w.x = (unsigned)f2bf(breg[i][0]) | ((unsigned)f2bf(breg[i][1]) << 16);
            w.y = (unsigned)f2bf(breg[i][2]) | ((unsigned)f2bf(breg[i][3]) << 16);
            *(uint2*)(Bsh + b_lds[i]) = w;
        }
        __syncthreads();

        // prefetch next tile into registers (overlaps with MFMA below)
        if (t + 1 < KSTEPS) {
            #pragma unroll
            for (int i = 0; i < 2; ++i)
                areg[i] = *(const int4*)(xnb + a_goff[i] + (t + 1) * BK);
            #pragma unroll
            for (int i = 0; i < 5; ++i) {
                const float* p = W + b_goff[i] + (t + 1) * (BK * CC);
                breg[i][0] = p[0];
                breg[i][1] = p[CC];
                breg[i][2] = p[2 * CC];
                breg[i][3] = p[3 * CC];
            }
        }

        // swapped operands: D[row=n][col=m] -> lane holds 4 consecutive n, 1 m
        #pragma unroll
        for (int ks = 0; ks < 2; ++ks) {
            bf16x8 af[2], bfr[5];
            #pragma unroll
            for (int mf = 0; mf < 2; ++mf)
                af[mf] = *(const bf16x8*)(Ash + swz(wm * 32 + mf * 16 + lr, ks * 64 + lg * 16));
            #pragma unroll
            for (int nf = 0; nf < 5; ++nf)
                bfr[nf] = *(const bf16x8*)(Bsh + swz(wn * 80 + nf * 16 + lr, ks * 64 + lg * 16));
            #pragma unroll
            for (int mf = 0; mf < 2; ++mf)
                #pragma unroll
                for (int nf = 0; nf < 5; ++nf)
                    acc[mf][nf] = __builtin_amdgcn_mfma_f32_16x16x32_bf16(
                        bfr[nf], af[mf], acc[mf][nf], 0, 0, 0);
        }
    }

    // ---- deterministic column-norm reduction (part[] in Bsh region) ----
    __syncthreads();                        // all waves done with LDS reads
    float* part = (float*)Bsh;              // [16][160] floats = 10240 B
    #pragma unroll
    for (int i = 0; i < 5; ++i)
        part[i * 512 + tid] = bsq[i];       // slot s = kq*160+n, unique owner
    __syncthreads();
    if (tid < BN) {
        float s = 0.f;
        #pragma unroll
        for (int k = 0; k < 16; ++k)
            s += part[k * BN + tid];        // fixed order -> deterministic
        rn[tid] = rsqrtf(fmaxf(s, 1e-12f));
    }
    __syncthreads();

    // ---- epilogue: LDS-staged transpose -> contiguous line-aligned row stores ----
    float* stag = (float*)LDS;              // 32 rows x ST_STRIDE floats = 20992 B
    #pragma unroll
    for (int rd = 0; rd < 4; ++rd) {
        if (wm == rd) {
            // this wave owns rows rd*32 .. rd*32+31 (local m = mf*16 + lr)
            #pragma unroll
            for (int nf = 0; nf < 5; ++nf) {
                const int nloc = wn * 80 + nf * 16 + lg * 4;
                const f32x4 rn4 = *(const f32x4*)(rn + nloc);
                #pragma unroll
                for (int mf = 0; mf < 2; ++mf) {
                    f32x4 o;
                    #pragma unroll
                    for (int r = 0; r < 4; ++r)
                        o[r] = acc[mf][nf][r] * rn4[r];
                    *(f32x4*)(stag + (mf * 16 + lr) * ST_STRIDE + nloc) = o;
                }
            }
        }
        __syncthreads();                    // staging visible
        // copy 32 rows x 160 floats out: 1280 float4 slots, fully line-covered
        for (int j = tid; j < 1280; j += 512) {
            const int m = j / 40;           // 40 float4 per row
            const int n = (j % 40) * 4;
            f32x4 o = *(const f32x4*)(stag + m * ST_STRIDE + n);
            *(f32x4*)(out + (size_t)(M0 + rd * 32 + m) * CC + N0 + n) = o;
        }
        __syncthreads();                    // staging free for next round
    }
}

// ---------------- K3: margin fixup at label positions ----------------
__global__ __launch_bounds__(512) void k_fix(const int* __restrict__ lab,
                                             float* __restrict__ out) {
    const int b = threadIdx.x;
    const int c = lab[b];
    const size_t idx = (size_t)b * CC + c;
    float t = out[idx];
    t = fminf(fmaxf(t, -1.f), 1.f);
    float th = acosf(t) + MARGIN2;
    th = fminf(th, PI_F);              // min(t, t + (pi - stopgrad(t))) value-wise
    out[idx] = cosf(th);               // M3 == 0: no additive term
}

extern "C" void kernel_launch(void* const* d_in, const int* in_sizes, int n_in,
                              void* d_out, int out_size, void* d_ws, size_t ws_size,
                              hipStream_t stream) {
    const float* x   = (const float*)d_in[0];
    const float* W   = (const float*)d_in[1];
    const int*   lab = (const int*)d_in[2];
    float* out = (float*)d_out;

    unsigned short* xnb = (unsigned short*)d_ws;   // 512*512*2 = 512 KB scratch

    k_norm_x<<<dim3(BB / 4), dim3(256), 0, stream>>>(x, xnb);
    k_gemm<<<dim3((BB / BM) * (CC / BN)), dim3(512), 0, stream>>>(xnb, W, out);
    k_fix<<<dim3(1), dim3(512), 0, stream>>>(lab, out);
}

// Round 5
// 157.398 us; speedup vs baseline: 2.3325x; 1.3451x over previous
//
#include <hip/hip_runtime.h>
#include <math.h>

#define BB 512       // batch rows (M)
#define DD 512       // depth (K)
#define CC 100000    // classes (N)
#define MARGIN2 0.5f
#define PI_F 3.14159265358979323846f

#define BM 256
#define BN 128
#define BK 64
#define KSTEPS (DD / BK)     // 8
#define NPAN 782             // ceil(100000/128), last panel 32 cols
#define GRID (2 * NPAN)      // 1564 blocks

typedef __bf16 bf16x8 __attribute__((ext_vector_type(8)));
typedef float f32x4 __attribute__((ext_vector_type(4)));

static __device__ __forceinline__ unsigned short f2bf(float f) {
    union { float f; unsigned u; } v; v.f = f;
    unsigned r = v.u + 0x7FFFu + ((v.u >> 16) & 1u);   // round-to-nearest-even
    return (unsigned short)(r >> 16);
}

// swizzled LDS byte offset for row-major [row][64 x bf16] tiles (row stride 128B)
static __device__ __forceinline__ int swz(int row, int kbyte) {
    return row * 128 + (kbyte ^ ((row & 7) << 4));
}

// async global->LDS, 16B per lane; LDS dest = wave-uniform base + lane*16 (HW rule)
static __device__ __forceinline__ void gll16(const unsigned char* g, unsigned char* l) {
    __builtin_amdgcn_global_load_lds(
        (const __attribute__((address_space(1))) void*)g,
        (__attribute__((address_space(3))) void*)l, 16, 0, 0);
}

// ---------------- K1: row-normalize x -> bf16, PRE-SWIZZLED A images ----------------
// Image layout: img[(mb*8 + t) * 32768 + swz(lrow, chunk*16) + sub*8], so that the
// GEMM's linear global_load_lds reproduces the swizzled Ash layout exactly (m173).
__global__ __launch_bounds__(256) void k_norm_x(const float* __restrict__ x,
                                                unsigned char* __restrict__ img) {
    const int lane = threadIdx.x & 63;
    const int row  = blockIdx.x * 4 + (threadIdx.x >> 6);
    const float* xr = x + (size_t)row * DD;
    float4 v0 = *(const float4*)(xr + lane * 4);
    float4 v1 = *(const float4*)(xr + lane * 4 + 256);
    float s = v0.x*v0.x + v0.y*v0.y + v0.z*v0.z + v0.w*v0.w
            + v1.x*v1.x + v1.y*v1.y + v1.z*v1.z + v1.w*v1.w;
    #pragma unroll
    for (int m = 32; m; m >>= 1) s += __shfl_xor(s, m, 64);
    float rs = rsqrtf(fmaxf(s, 1e-12f));
    ushort4 o0, o1;
    o0.x = f2bf(v0.x * rs); o0.y = f2bf(v0.y * rs);
    o0.z = f2bf(v0.z * rs); o0.w = f2bf(v0.w * rs);
    o1.x = f2bf(v1.x * rs); o1.y = f2bf(v1.y * rs);
    o1.z = f2bf(v1.z * rs); o1.w = f2bf(v1.w * rs);

    const int mb   = row >> 8;            // which 256-row M block
    const int lrow = row & 255;
    const int k0   = lane * 4;            // v0 covers k0..k0+3; v1 covers k0+256..
    const int t0   = k0 >> 6;             // 0..3 (v1 -> t0+4)
    const int c8   = (k0 >> 3) & 7;       // 16B chunk within 128B row
    const int sub  = (k0 >> 2) & 1;       // 8B half of the chunk
    const int base = (mb * 8 + t0) * 32768 + lrow * 128
                   + ((c8 * 16) ^ ((lrow & 7) << 4)) + sub * 8;
    *(ushort4*)(img + base)          = o0;
    *(ushort4*)(img + base + 131072) = o1;   // t0+4 image (4 * 32768)
}

// ---------------- K2: bf16 MFMA GEMM, 256x128 tile, per-wave 64x64 ----------------
// LDS: bufA = 2 x 32KB (double-buffered, filled by global_load_lds from image)
//      Bsh  = 16KB single buffer ([n][64k] bf16 swizzled), cvt_pk from fp32 W
// After K loop: Bsh head -> part[16][128] + rn[128]; bufA head -> store staging.
__global__ __launch_bounds__(512, 2) void k_gemm(const unsigned char* __restrict__ img,
                                                 const float* __restrict__ W,
                                                 float* __restrict__ out) {
    __shared__ __align__(16) unsigned char LDS[81920];
    unsigned char* bufA = LDS;              // 2 x 32768
    unsigned char* Bsh  = LDS + 65536;      // 16384

    const int tid = threadIdx.x;
    const int bid = blockIdx.x;

    // bijective XCD swizzle (1564 = 8*195 + 4): mb-pairs of a W panel share one XCD's L2
    const int xcd = bid & 7;
    const int jj  = bid >> 3;
    const int v   = (xcd < 4) ? (xcd * 196 + jj) : (784 + (xcd - 4) * 195 + jj);
    const int mb  = v & 1;
    const int nb  = v >> 1;
    const int M0 = mb * BM;
    const int N0 = nb * BN;

    const int lane = tid & 63;
    const int wid  = tid >> 6;
    const int wm = wid >> 1;       // 0..3 -> 64 rows each
    const int wn = wid & 1;        // 0..1 -> 64 cols each
    const int lr = lane & 15;
    const int lg = lane >> 4;

    // ---- B staging tasks: 4 per thread; s = kq*128 + n (bijective, also part[] slot) ----
    int b_go[4], b_ld[4];
    #pragma unroll
    for (int i = 0; i < 4; ++i) {
        int s  = tid + i * 512;
        int n  = s & 127;
        int kq = s >> 7;                       // 0..15, quad of k
        int col = N0 + n;
        col = col < CC ? col : CC - 1;         // tail-panel clamp (dead cols)
        b_go[i] = kq * 4 * CC + col;
        b_ld[i] = n * 128 + ((kq * 8) ^ ((n & 7) << 4));
    }

    const unsigned char* imgA = img + mb * (8 * 32768);
    const int lds_u = wid * 1024;              // wave-uniform part of linear offset

    float breg[4][4];
    float bsq[4] = {0.f, 0.f, 0.f, 0.f};

    // prologue: tile 0 -> regs (B) and bufA[0] (A via gll)
    #pragma unroll
    for (int i = 0; i < 4; ++i) {
        const float* p = W + b_go[i];
        breg[i][0] = p[0]; breg[i][1] = p[CC];
        breg[i][2] = p[2 * CC]; breg[i][3] = p[3 * CC];
    }
    #pragma unroll
    for (int i = 0; i < 4; ++i)
        gll16(imgA + i * 8192 + lds_u + lane * 16, bufA + i * 8192 + lds_u);

    f32x4 acc[4][4];
    #pragma unroll
    for (int mf = 0; mf < 4; ++mf)
        #pragma unroll
        for (int nf = 0; nf < 4; ++nf)
            acc[mf][nf] = (f32x4)0.f;

    for (int t = 0; t < KSTEPS; ++t) {
        unsigned char* A_cur = bufA + (t & 1) * 32768;
        // b1: per-wave vmcnt drain (A(t) gll + B(t) regs) + wait all waves done
        // reading tile t-1 LDS
        __syncthreads();
        // write B(t): cvt_pk fp32->bf16 pairs + swizzled ds_write_b64; fuse sumsq
        #pragma unroll
        for (int i = 0; i < 4; ++i) {
            bsq[i] += breg[i][0] * breg[i][0] + breg[i][1] * breg[i][1]
                    + breg[i][2] * breg[i][2] + breg[i][3] * breg[i][3];
            unsigned w0, w1;
            asm("v_cvt_pk_bf16_f32 %0, %1, %2" : "=v"(w0) : "v"(breg[i][0]), "v"(breg[i][1]));
            asm("v_cvt_pk_bf16_f32 %0, %1, %2" : "=v"(w1) : "v"(breg[i][2]), "v"(breg[i][3]));
            uint2 w; w.x = w0; w.y = w1;
            *(uint2*)(Bsh + b_ld[i]) = w;
        }
        __syncthreads();   // b2: Bsh(t) visible; all waves' A(t) glls completed pre-b1
        // prefetch tile t+1 (stays in flight through compute; drained at next b1)
        if (t + 1 < KSTEPS) {
            #pragma unroll
            for (int i = 0; i < 4; ++i) {
                const float* p = W + b_go[i] + (t + 1) * (BK * CC);
                breg[i][0] = p[0]; breg[i][1] = p[CC];
                breg[i][2] = p[2 * CC]; breg[i][3] = p[3 * CC];
            }
            unsigned char* A_nxt = bufA + ((t + 1) & 1) * 32768;
            const unsigned char* gsrc = imgA + (t + 1) * 32768;
            #pragma unroll
            for (int i = 0; i < 4; ++i)
                gll16(gsrc + i * 8192 + lds_u + lane * 16, A_nxt + i * 8192 + lds_u);
        }
        // compute tile t: 2 k-substeps, 4x4 fragments, swapped operands
        #pragma unroll
        for (int ks = 0; ks < 2; ++ks) {
            bf16x8 af[4], bfr[4];
            #pragma unroll
            for (int mf = 0; mf < 4; ++mf)
                af[mf] = *(const bf16x8*)(A_cur + swz(wm * 64 + mf * 16 + lr, ks * 64 + lg * 16));
            #pragma unroll
            for (int nf = 0; nf < 4; ++nf)
                bfr[nf] = *(const bf16x8*)(Bsh + swz(wn * 64 + nf * 16 + lr, ks * 64 + lg * 16));
            #pragma unroll
            for (int mf = 0; mf < 4; ++mf)
                #pragma unroll
                for (int nf = 0; nf < 4; ++nf)
                    acc[mf][nf] = __builtin_amdgcn_mfma_f32_16x16x32_bf16(
                        bfr[nf], af[mf], acc[mf][nf], 0, 0, 0);
        }
    }

    // ---- deterministic column-norm reduction (reuse Bsh) ----
    __syncthreads();
    float* part = (float*)Bsh;                 // [16][128] floats = 8KB
    #pragma unroll
    for (int i = 0; i < 4; ++i)
        part[tid + i * 512] = bsq[i];          // slot = kq*128+n, unique owner
    __syncthreads();
    float* rn = (float*)(Bsh + 8192);          // [128] floats
    if (tid < BN) {
        float s = 0.f;
        #pragma unroll
        for (int k = 0; k < 16; ++k)
            s += part[k * BN + tid];           // fixed order -> deterministic
        rn[tid] = rsqrtf(fmaxf(s, 1e-12f));
    }
    __syncthreads();

    // ---- epilogue: LDS-staged -> 512B-aligned full-sector row stores ----
    float* stag = (float*)bufA;                // 32 rows x 132 floats
    #pragma unroll
    for (int rd = 0; rd < 8; ++rd) {
        if (wm == (rd >> 1)) {
            #pragma unroll
            for (int f = 0; f < 2; ++f) {
                const int mf = (rd & 1) * 2 + f;
                const int ml = f * 16 + lr;
                #pragma unroll
                for (int nf = 0; nf < 4; ++nf) {
                    const int nl = wn * 64 + nf * 16 + lg * 4;
                    const f32x4 rn4 = *(const f32x4*)(rn + nl);
                    f32x4 o;
                    #pragma unroll
                    for (int r = 0; r < 4; ++r)
                        o[r] = acc[mf][nf][r] * rn4[r];
                    *(f32x4*)(stag + ml * 132 + nl) = o;
                }
            }
        }
        __syncthreads();
        #pragma unroll
        for (int j = tid; j < 1024; j += 512) {
            const int m = j >> 5;
            const int n = (j & 31) * 4;
            if (N0 + n + 4 <= CC) {
                f32x4 o = *(const f32x4*)(stag + m * 132 + n);
                *(f32x4*)(out + (size_t)(M0 + rd * 32 + m) * CC + N0 + n) = o;
            }
        }
        __syncthreads();
    }
}

// ---------------- K3: margin fixup at label positions ----------------
__global__ __launch_bounds__(512) void k_fix(const int* __restrict__ lab,
                                             float* __restrict__ out) {
    const int b = threadIdx.x;
    const int c = lab[b];
    const size_t idx = (size_t)b * CC + c;
    float t = out[idx];
    t = fminf(fmaxf(t, -1.f), 1.f);
    float th = acosf(t) + MARGIN2;
    th = fminf(th, PI_F);              // min(t, t + (pi - stopgrad(t))) value-wise
    out[idx] = cosf(th);               // M3 == 0: no additive term
}

extern "C" void kernel_launch(void* const* d_in, const int* in_sizes, int n_in,
                              void* d_out, int out_size, void* d_ws, size_t ws_size,
                              hipStream_t stream) {
    const float* x   = (const float*)d_in[0];
    const float* W   = (const float*)d_in[1];
    const int*   lab = (const int*)d_in[2];
    float* out = (float*)d_out;

    unsigned char* img = (unsigned char*)d_ws;   // 512KB pre-swizzled xn images

    k_norm_x<<<dim3(BB / 4), dim3(256), 0, stream>>>(x, img);
    k_gemm<<<dim3(GRID), dim3(512), 0, stream>>>(img, W, out);
    k_fix<<<dim3(1), dim3(512), 0, stream>>>(lab, out);
}